// Round 2
// baseline (130.384 us; speedup 1.0000x reference)
//
#include <hip/hip_runtime.h>
#include <math.h>

// ---- band LUT: 1024 float2 over d in [-0.33, 1.3084), h = 0.0016 ----
// q is a BYTE index: q = (d - LO) * (8/h); entry = (f0 - 8i*D8, D8=(f1-f0)/8)
// f(d) ~= e.x + q * e.y   (exact lerp, no fraction extraction needed)
#define LUT_N   1024
#define LUT_H   0.0016
#define LUT_LO  (-0.33)
#define INVH8   5000.0f          // 8 / LUT_H
#define QMAX    8184.0f          // (LUT_N-1) * 8
#define BAND_LO (-0.35f)
#define BAND_HI (1.28f)

// ---- ws layout (bytes) ----
#define WS_LUT    0              // float2[1024]   8192
#define WS_TH2T   8192           // float[36864]   147456 -> 155648
#define WS_RAW1   155648         // float[262144]  1048576 -> 1204224
#define WS_MASK   1204224        // u64[4096]      32768  -> 1236992
#define WS_SUMS1  1236992        // float[128]     512    -> 1237504
#define WS_SUMS2  1237504        // float[128]     512    -> 1238016
#define WS_MM     1238016        // u32[2]         8      -> 1238024
#define WS_TOTAL  1238024

__device__ __forceinline__ double f_exact(double d) {
    const double nvt = 1.5 * 0.026;
    double a1 = d / nvt;         a1 = fmin(fmax(a1, -30.0), 30.0);
    double a2 = (d - 0.1) / nvt; a2 = fmin(fmax(a2, -30.0), 30.0);
    double s1 = log1p(exp(a1));
    double s2 = log1p(exp(a2));
    return 0.0005625 * (s1 * s1 - s2 * s2);
}

// K0: blk<4 LUT | blk<148 theta2 transpose + min/max | else prescaled x (pixel-major)
__global__ __launch_bounds__(256) void k0_prep(
    const float* __restrict__ x, const float* __restrict__ theta2,
    const float* __restrict__ psc, const float* __restrict__ psh,
    float2* __restrict__ lutg, float* __restrict__ th2t,
    float* __restrict__ xs, unsigned* __restrict__ mm)
{
    int blk = blockIdx.x, tid = threadIdx.x;
    if (blk < 4) {
        int i = blk * 256 + tid;                       // 0..1023
        double d0 = LUT_LO + (double)i * LUT_H;
        double f0 = f_exact(d0), f1 = f_exact(d0 + LUT_H);
        double d8 = (f1 - f0) * 0.125;
        double ex = f0 - (double)(8 * i) * d8;
        lutg[i] = make_float2((float)ex, (float)d8);
    } else if (blk < 148) {
        int i = (blk - 4) * 256 + tid;                 // 0..36863
        int p = i & 63, k = i >> 6;
        float v = theta2[p * 576 + k];
        th2t[k * 64 + p] = v;
        __shared__ float smin[256], smax[256];
        smin[tid] = v; smax[tid] = v;
        __syncthreads();
        for (int s = 128; s > 0; s >>= 1) {
            if (tid < s) {
                smin[tid] = fminf(smin[tid], smin[tid + s]);
                smax[tid] = fmaxf(smax[tid], smax[tid + s]);
            }
            __syncthreads();
        }
        if (tid == 0) {
            atomicMax(&mm[0], __float_as_uint(smax[0]));     // positive floats: uint order ok
            atomicMax(&mm[1], ~__float_as_uint(smin[0]));    // min via complement, 0-init ok
        }
    } else {
        int idx = (blk - 148) * 256 + tid;             // 0..262143
        int c = idx & 63, gp = idx >> 6;
        int b = gp >> 10, pp = gp & 1023;
        float xv = x[b * 65536 + c * 1024 + pp];
        float sc = psc[0] * INVH8;
        float sh = (psh[0] + 0.33f) * INVH8;           // (psh - LUT_LO) * INVH8
        xs[idx] = fmaf(xv, sc, sh);                    // vb = (v - LO)*8/h
    }
}

// K1: dense conv1. grid 1024 = b(4) x yp(16) x pg(16); wave = 1 plane, 2 rows.
#define TAP(V, TH) {                                            \
    float th_ = (TH);                                           \
    float q_ = fmaf(th_, -INVH8, (V));                          \
    q_ = fminf(fmaxf(q_, 0.f), QMAX);                           \
    int ib_ = (int)q_ & ~7;                                     \
    float2 e_ = *(const float2*)((const char*)lut + ib_);       \
    acc = fmaf(q_, e_.y, acc + e_.x);                           \
}

__global__ __launch_bounds__(256) void k1_conv1(
    const float* __restrict__ xs, const float* __restrict__ theta1,
    const float* __restrict__ ls1, const float2* __restrict__ lutg,
    float* __restrict__ raw1, float* __restrict__ sums1)
{
    __shared__ float2 lut[LUT_N];
    {
        const float4* s = (const float4*)lutg;
        float4* d = (float4*)lut;
        for (int i = threadIdx.x; i < LUT_N / 2; i += 256) d[i] = s[i];
    }
    __syncthreads();

    int blk = blockIdx.x;
    int wv = __builtin_amdgcn_readfirstlane((int)threadIdx.x >> 6);
    int lane = threadIdx.x & 63;
    int p  = (blk & 15) * 4 + wv;
    int yp = (blk >> 4) & 15;
    int b  = blk >> 8;
    int r = lane >> 5, xc = lane & 31;
    int y = yp * 2 + r;

    const float* tpp = theta1 + p * 576;
    float acc = 0.f;

    for (int jy = 0; jy < 3; ++jy) {
        int ny = y + jy - 1;
        if ((unsigned)ny >= 32u) continue;
        for (int jx = 0; jx < 3; ++jx) {
            int nx = xc + jx - 1;
            if ((unsigned)nx >= 32u) continue;
            const float4* px4 = (const float4*)(xs + (((b << 10) + ny * 32 + nx) << 6));
            const float* tp = tpp + (jy * 3 + jx);
            #pragma unroll 4
            for (int cc = 0; cc < 16; ++cc) {
                float4 vb = px4[cc];
                const float* tq = tp + cc * 36;        // (cc*4)*9
                TAP(vb.x, tq[0]);
                TAP(vb.y, tq[9]);
                TAP(vb.z, tq[18]);
                TAP(vb.w, tq[27]);
            }
        }
    }
    float r1 = ls1[0] * acc;
    raw1[(((b << 6) + p) << 10) + y * 32 + xc] = r1;

    // BN1 partial sums (replaces old k2): wave reduce + one atomic per wave
    float lsum = r1, lsq = r1 * r1;
    for (int s = 32; s > 0; s >>= 1) {
        lsum += __shfl_xor(lsum, s);
        lsq  += __shfl_xor(lsq, s);
    }
    if (lane == 0) {
        atomicAdd(&sums1[p], lsum);
        atomicAdd(&sums1[64 + p], lsq);
    }
}

// K3: BN1 apply in place (stats finalized inline) + activity masks for sparse conv2
__global__ __launch_bounds__(256) void k3_bn1mask(float* __restrict__ v2,
    const float* __restrict__ sums1, const float* __restrict__ g1,
    const float* __restrict__ b1, const unsigned* __restrict__ mm,
    unsigned long long* __restrict__ masks)
{
    int idx = blockIdx.x * 256 + threadIdx.x;          // < 262144
    int c = (idx >> 10) & 63;
    float m   = sums1[c] * (1.f / 4096.f);
    float var = sums1[64 + c] * (1.f / 4096.f) - m * m;
    var = fmaxf(var, 0.f);
    float rstd = rsqrtf(var + 1e-5f);
    float v = v2[idx];
    v = (v - m) * rstd * g1[c] + b1[c];
    v2[idx] = v;
    float tmax = __uint_as_float(mm[0]);
    float tmin = __uint_as_float(~mm[1]);
    if (v > tmin + BAND_LO && v < tmax + BAND_HI) {
        int b = idx >> 16, pix = idx & 1023;
        atomicOr(&masks[b * 1024 + pix], 1ull << c);
    }
}

// K4: sparse conv2. grid 1024, wave per pixel, lane = output plane. Exact f32 eval.
__global__ __launch_bounds__(256) void k4_conv2(const float* __restrict__ v2,
    const float* __restrict__ th2t, const unsigned long long* __restrict__ masks,
    const float* __restrict__ ls2, float* __restrict__ out, float* __restrict__ sums2)
{
    int wv = __builtin_amdgcn_readfirstlane((int)threadIdx.x >> 6);
    int lane = threadIdx.x & 63;
    int P = blockIdx.x * 4 + wv;                       // 0..4095
    int b = P >> 10, rem = P & 1023;
    int y = rem >> 5, xq = rem & 31;
    float l2 = ls2[0];
    const float inv_nvt = (float)(1.0 / (1.5 * 0.026));
    float acc = 0.f;

    #pragma unroll
    for (int j = 0; j < 9; ++j) {
        int ny = y + j / 3 - 1, nx = xq + j % 3 - 1;
        if ((unsigned)ny < 32u && (unsigned)nx < 32u) {
            unsigned long long mk = masks[b * 1024 + ny * 32 + nx];
            while (mk) {
                int c = __ffsll((long long)mk) - 1;
                mk &= mk - 1;
                float v  = v2[((b * 64 + c) * 32 + ny) * 32 + nx];  // wave-uniform
                float th = th2t[(c * 9 + j) * 64 + lane];           // coalesced
                float d = v - th;
                if (d > BAND_LO && d < BAND_HI) {
                    float a1 = fminf(fmaxf(d * inv_nvt, -30.f), 30.f);
                    float a2 = fminf(fmaxf((d - 0.1f) * inv_nvt, -30.f), 30.f);
                    float s1 = __logf(1.f + __expf(a1));
                    float s2 = __logf(1.f + __expf(a2));
                    acc += (s1 * s1 - s2 * s2);
                }
            }
        }
    }
    float r2 = 0.0005625f * l2 * acc;
    out[((b * 64 + lane) * 32 + y) * 32 + xq] = r2;

    __shared__ float ss[256], sq[256];
    ss[threadIdx.x] = r2; sq[threadIdx.x] = r2 * r2;
    __syncthreads();
    if (threadIdx.x < 64) {
        float a  = ss[threadIdx.x] + ss[threadIdx.x + 64] + ss[threadIdx.x + 128] + ss[threadIdx.x + 192];
        float qq = sq[threadIdx.x] + sq[threadIdx.x + 64] + sq[threadIdx.x + 128] + sq[threadIdx.x + 192];
        atomicAdd(&sums2[threadIdx.x], a);
        atomicAdd(&sums2[64 + threadIdx.x], qq);
    }
}

// K6: BN2 apply (stats finalized inline) + residual add, in place on d_out
__global__ __launch_bounds__(256) void k6_final(float* __restrict__ out,
    const float* __restrict__ x, const float* __restrict__ sums2,
    const float* __restrict__ g2, const float* __restrict__ b2)
{
    int idx = blockIdx.x * 256 + threadIdx.x;          // < 262144
    int p = (idx >> 10) & 63;
    float m   = sums2[p] * (1.f / 4096.f);
    float var = sums2[64 + p] * (1.f / 4096.f) - m * m;
    var = fmaxf(var, 0.f);
    float rstd = rsqrtf(var + 1e-5f);
    out[idx] = (out[idx] - m) * rstd * g2[p] + b2[p] + x[idx];
}

extern "C" void kernel_launch(void* const* d_in, const int* in_sizes, int n_in,
                              void* d_out, int out_size, void* d_ws, size_t ws_size,
                              hipStream_t stream)
{
    const float* x   = (const float*)d_in[0];
    const float* th1 = (const float*)d_in[1];
    const float* th2 = (const float*)d_in[2];
    const float* psc = (const float*)d_in[3];
    const float* psh = (const float*)d_in[4];
    const float* l1  = (const float*)d_in[5];
    const float* l2  = (const float*)d_in[6];
    const float* g1  = (const float*)d_in[7];
    const float* b1  = (const float*)d_in[8];
    const float* g2  = (const float*)d_in[9];
    const float* b2  = (const float*)d_in[10];
    float* out = (float*)d_out;
    char* ws = (char*)d_ws;
    if (ws_size < (size_t)WS_TOTAL) return;  // defensive: leave output poisoned -> loud fail

    float2* lutg = (float2*)(ws + WS_LUT);
    float*  th2t = (float*)(ws + WS_TH2T);
    float*  raw1 = (float*)(ws + WS_RAW1);
    unsigned long long* masks = (unsigned long long*)(ws + WS_MASK);
    float*  sums1 = (float*)(ws + WS_SUMS1);
    float*  sums2 = (float*)(ws + WS_SUMS2);
    unsigned* mm  = (unsigned*)(ws + WS_MM);

    float* xs = out;  // d_out used as scratch for prescaled x until K4 overwrites it

    // one memset covers masks + sums1 + sums2 + mm (mm min uses complement trick)
    hipMemsetAsync(ws + WS_MASK, 0, WS_TOTAL - WS_MASK, stream);

    k0_prep   <<<1172, 256, 0, stream>>>(x, th2, psc, psh, lutg, th2t, xs, mm);
    k1_conv1  <<<1024, 256, 0, stream>>>(xs, th1, l1, lutg, raw1, sums1);
    k3_bn1mask<<<1024, 256, 0, stream>>>(raw1, sums1, g1, b1, mm, masks);
    k4_conv2  <<<1024, 256, 0, stream>>>(raw1, th2t, masks, l2, out, sums2);
    k6_final  <<<1024, 256, 0, stream>>>(out, x, sums2, g2, b2);
}